// Round 11
// baseline (631.972 us; speedup 1.0000x reference)
//
#include <hip/hip_runtime.h>
#include <hip/hip_bf16.h>
#include <stdint.h>

typedef __attribute__((ext_vector_type(8))) short short8;
typedef __attribute__((ext_vector_type(4))) short short4v;
typedef __attribute__((ext_vector_type(4))) float floatx4;
typedef unsigned long long u64;

typedef __attribute__((address_space(1))) const uint32_t ga_u32;
typedef __attribute__((address_space(3))) uint32_t ls_u32;

static constexpr int NROWS = 32768;
static constexpr int NCODE = 8192;
static constexpr int QELEMS = 8388608;

static __device__ __forceinline__ short bf16bits(float v) {
  __hip_bfloat16 h = __float2bfloat16(v);
  return *reinterpret_cast<short*>(&h);
}

// ---- fused prep: [0,1024) z-transpose, [1024,3072) codebook+norms ----
__global__ __launch_bounds__(256) void prep_all(
    const float* __restrict__ z, const float* __restrict__ cb,
    __hip_bfloat16* __restrict__ zh, __hip_bfloat16* __restrict__ chv,
    float* __restrict__ norms)
{
  const int bid = blockIdx.x;
  const int t = threadIdx.x;
  if (bid < 1024) {
    __shared__ float tile[32][260];
    const int b = bid & 31, db = (bid >> 5) & 7, hwb = bid >> 8;
    const int d0 = db * 32, hw0 = hwb * 256;
    const float* src = z + (((size_t)b * 256 + d0) << 10) + hw0;
#pragma unroll
    for (int i = 0; i < 8; ++i) {
      int idx = i * 256 + t;
      int r = idx >> 6, c4 = (idx & 63) * 4;
      *(floatx4*)&tile[r][c4] = *(const floatx4*)&src[((size_t)r << 10) + c4];
    }
    __syncthreads();
    const int dq = t & 3;
    const int hb = t >> 2;
#pragma unroll
    for (int it = 0; it < 4; ++it) {
      int h = hb + it * 64;
      short8 o;
#pragma unroll
      for (int i = 0; i < 8; ++i) o[i] = bf16bits(tile[dq * 8 + i][h]);
      *(short8*)&zh[((size_t)(b * 1024 + hw0 + h)) * 256 + d0 + dq * 8] = o;
    }
  } else {
    const int k = (bid - 1024) * 4 + (t >> 6);
    const int lane = t & 63;
    floatx4 v = *(const floatx4*)&cb[((size_t)k << 8) + lane * 4];
    short4v o;
#pragma unroll
    for (int i = 0; i < 4; ++i) o[i] = bf16bits(v[i]);
    *(short4v*)&chv[((size_t)k << 8) + lane * 4] = o;
    float s = v[0] * v[0] + v[1] * v[1] + v[2] * v[2] + v[3] * v[3];
#pragma unroll
    for (int off = 32; off; off >>= 1) s += __shfl_down(s, off);
    if (lane == 0) norms[k] = s;
  }
}

// ---- main: A-in-regs, per-wave private B ring, ZERO barriers in K-loop ----
// 256 blocks (64 code panels x 4 zrow quarters) x 512 thr (2 wm x 4 wn waves).
// Wave: 64 codes (af[4][8] regs, K=256) x 64 zrows/tile; 32 tiles x 8 K-steps
// = 256 pipeline steps, per-wave counted vmcnt(4), no __syncthreads.
__global__ __launch_bounds__(512, 2) void gemm_argmin(
    const __hip_bfloat16* __restrict__ zh, const __hip_bfloat16* __restrict__ chv,
    const float* __restrict__ norms, u64* __restrict__ partial)
{
  // [0,49152) ushorts: 8 waves x 3 slots x 2048 (B ring; A-bounce in prologue)
  __shared__ alignas(16) unsigned short lds[49152];
  __shared__ alignas(16) u64 best2[512];

  const int tid = threadIdx.x;
  const int lane = tid & 63;
  const int wid = tid >> 6;
  const int wm = wid >> 2;   // code half (64 codes)
  const int wn = wid & 3;    // zrow quarter within tile (64 zrows)

  const int bid = blockIdx.x;
  const int pnl = bid >> 2;      // 64 code panels
  const int qt = bid & 3;        // 4 zrow quarters
  const int m0 = pnl * 128;
  const int nbase = qt * 8192;

  const int q = lane & 15;
  const int g = lane >> 4;
  const int rchunk = ((g ^ ((q >> 1) & 3)) << 3);  // verified swizzle (ushorts)

  // ---- norms -> regs (vmem; drains at prologue vmcnt(0)) ----
  float nrm[4][4];
#pragma unroll
  for (int i = 0; i < 4; ++i)
#pragma unroll
    for (int r = 0; r < 4; ++r)
      nrm[i][r] = norms[m0 + wm * 64 + i * 16 + g * 4 + r];

  // ---- prologue: A (128 codes x 256 k) -> LDS bounce -> af regs ----
  // LDS layout [128 rows][256 elems]; chunk-slot cs = pp*512+tid (16B each)
#pragma unroll
  for (int pp = 0; pp < 8; ++pp) {
    const __hip_bfloat16* gA = chv + ((size_t)(m0 + pp * 16 + (tid >> 5)) << 8) + (tid & 31) * 8;
    __builtin_amdgcn_global_load_lds((ga_u32*)gA, (ls_u32*)(lds + (pp * 512 + tid) * 8), 16, 0, 0);
  }
  asm volatile("s_waitcnt vmcnt(0)" ::: "memory");
  __builtin_amdgcn_s_barrier();
  asm volatile("" ::: "memory");

  short8 af[4][8];  // [code tile][k-step] — constant across all 32 zrow tiles
#pragma unroll
  for (int i = 0; i < 4; ++i)
#pragma unroll
    for (int ks = 0; ks < 8; ++ks)
      af[i][ks] = *(const short8*)(lds + (size_t)(wm * 64 + i * 16 + q) * 256 + ks * 32 + g * 8);
  asm volatile("s_waitcnt lgkmcnt(0)" ::: "memory");
  __builtin_amdgcn_sched_barrier(0);
  __builtin_amdgcn_s_barrier();  // all waves done with A region before B staging
  asm volatile("" ::: "memory");

  unsigned short* wbase = lds + wid * 6144;  // private: 3 slots x 2048 ushorts

  // stage logical step sl (tile sl>>3, kstep sl&7) into private slot st
  auto STAGE = [&](int sl, int st) {
    const int tt = sl >> 3, kt = sl & 7;
    const __hip_bfloat16* gB = zh + ((size_t)(nbase + tt * 256 + wn * 64) << 8) + kt * 32;
    unsigned short* dst = wbase + st * 2048;
    const int srcoff = (((lane & 3) ^ ((lane >> 3) & 3)) << 3);
#pragma unroll
    for (int pp = 0; pp < 4; ++pp) {
      const __hip_bfloat16* gp = gB + ((size_t)(pp * 16 + (lane >> 2)) << 8) + srcoff;
      __builtin_amdgcn_global_load_lds((ga_u32*)gp, (ls_u32*)(dst + pp * 512 + lane * 8), 16, 0, 0);
    }
  };

  floatx4 acc[4][4];
#pragma unroll
  for (int i = 0; i < 4; ++i)
#pragma unroll
    for (int j = 0; j < 4; ++j)
      acc[i][j] = (floatx4){0.f, 0.f, 0.f, 0.f};

  STAGE(0, 0);
  STAGE(1, 1);
  asm volatile("s_waitcnt vmcnt(4)" ::: "memory");  // step0 landed, step1 in flight

#pragma unroll 1
  for (int t = 0; t < 32; ++t) {
#pragma unroll
    for (int kt = 0; kt < 8; ++kt) {
      const int s = t * 8 + kt;
      const int slot = s % 3;
      short8 bf[4];
#pragma unroll
      for (int j = 0; j < 4; ++j)
        bf[j] = *(const short8*)(wbase + slot * 2048 + (j * 16 + q) * 32 + rchunk);
      STAGE((s + 2) & 255, (s + 2) % 3);  // wrapped tail keeps pipeline uniform
      __builtin_amdgcn_s_setprio(1);
#pragma unroll
      for (int i = 0; i < 4; ++i)
#pragma unroll
        for (int j = 0; j < 4; ++j)
          acc[i][j] = __builtin_amdgcn_mfma_f32_16x16x32_bf16(af[i][kt], bf[j], acc[i][j], 0, 0, 0);
      __builtin_amdgcn_s_setprio(0);
      asm volatile("s_waitcnt lgkmcnt(0)" ::: "memory");  // bf consumed; slot reusable
      __builtin_amdgcn_sched_barrier(0);
      asm volatile("s_waitcnt vmcnt(4)" ::: "memory");    // stage(s+1) landed
    }

    // ---- tile epilogue (raw s_barrier + lgkm only; stages stay in flight) ----
#pragma unroll
    for (int j = 0; j < 4; ++j) {
      float best = __builtin_inff();
      int bc = 0;
#pragma unroll
      for (int i = 0; i < 4; ++i)
#pragma unroll
        for (int r = 0; r < 4; ++r) {
          float sc = fmaf(acc[i][j][r], -2.0f, nrm[i][r]);
          int cd = m0 + wm * 64 + i * 16 + g * 4 + r;
          if (sc < best) { best = sc; bc = cd; }
        }
      uint32_t u = __float_as_uint(best);
      u ^= ((uint32_t)((int32_t)u >> 31) | 0x80000000u);  // monotone-sortable
      u64 p = ((u64)u << 32) | (uint32_t)bc;
#pragma unroll
      for (int off = 16; off < 64; off <<= 1) {
        u64 o = (u64)__shfl_xor((long long)p, off);
        p = o < p ? o : p;
      }
      if (lane < 16) best2[(wn * 64 + j * 16 + lane) * 2 + wm] = p;
#pragma unroll
      for (int i = 0; i < 4; ++i) acc[i][j] = (floatx4){0.f, 0.f, 0.f, 0.f};
    }
    asm volatile("s_waitcnt lgkmcnt(0)" ::: "memory");
    __builtin_amdgcn_s_barrier();
    asm volatile("" ::: "memory");
    if (tid < 256) {
      u64 a = best2[tid * 2], b = best2[tid * 2 + 1];
      partial[(size_t)pnl * NROWS + nbase + t * 256 + tid] = a < b ? a : b;
    }
    asm volatile("s_waitcnt lgkmcnt(0)" ::: "memory");  // best2 reads done
    __builtin_amdgcn_s_barrier();
    asm volatile("" ::: "memory");
  }
}

// ---- reduce 64 panel partials -> final code (deterministic, no atomics) ----
__global__ __launch_bounds__(256) void reduce_amin(const u64* __restrict__ partial,
                                                   uint32_t* __restrict__ codei)
{
  const int n = blockIdx.x * 256 + threadIdx.x;
  u64 m = partial[n];
#pragma unroll 4
  for (int x = 1; x < 64; ++x) {
    u64 v = partial[(size_t)x * NROWS + n];
    m = v < m ? v : m;
  }
  codei[n] = (uint32_t)m;
}

// ---- gather + output + per-block loss partials (8 elems/thread) ----
__global__ __launch_bounds__(256) void gather_out(
    const float* __restrict__ z, const float* __restrict__ cb,
    const uint32_t* __restrict__ codei,
    float* __restrict__ out, float* __restrict__ partial)
{
  const int t = threadIdx.x;
  const size_t e0 = ((size_t)blockIdx.x * 256 + t) * 8;
  const int d = (int)((e0 >> 10) & 255);
  const int b = (int)(e0 >> 18);
  const int n0 = b * 1024 + (int)(e0 & 1023);
  uint32_t kv[8];
#pragma unroll
  for (int m = 0; m < 8; ++m) kv[m] = codei[n0 + m];
  floatx4 z0 = *(const floatx4*)&z[e0];
  floatx4 z1 = *(const floatx4*)&z[e0 + 4];
  floatx4 q0, q1;
#pragma unroll
  for (int m = 0; m < 4; ++m) {
    q0[m] = cb[((size_t)kv[m] << 8) + d];
    q1[m] = cb[((size_t)kv[4 + m] << 8) + d];
  }
  *(floatx4*)&out[e0] = q0;
  *(floatx4*)&out[e0 + 4] = q1;
  float s = 0.f;
#pragma unroll
  for (int m = 0; m < 4; ++m) {
    float d0 = z0[m] - q0[m], d1 = z1[m] - q1[m];
    s += d0 * d0 + d1 * d1;
  }
#pragma unroll
  for (int off = 32; off; off >>= 1) s += __shfl_down(s, off);
  __shared__ float ps[4];
  if ((t & 63) == 0) ps[t >> 6] = s;
  __syncthreads();
  if (t == 0) partial[blockIdx.x] = ps[0] + ps[1] + ps[2] + ps[3];
}

// ---- deterministic final reduction + scalar outputs ----
__global__ __launch_bounds__(256) void finalize(const float* __restrict__ partial,
                                                float* __restrict__ out)
{
  const int t = threadIdx.x;
  float s = 0.f;
#pragma unroll
  for (int i = 0; i < 16; ++i) s += partial[i * 256 + t];
#pragma unroll
  for (int off = 32; off; off >>= 1) s += __shfl_down(s, off);
  __shared__ float ps[4];
  if ((t & 63) == 0) ps[t >> 6] = s;
  __syncthreads();
  if (t == 0) {
    float m = (ps[0] + ps[1] + ps[2] + ps[3]) / (float)QELEMS;
    out[QELEMS] = m;             // codebook_loss
    out[QELEMS + 1] = 0.2f * m;  // commitment_loss
  }
}

extern "C" void kernel_launch(void* const* d_in, const int* in_sizes, int n_in,
                              void* d_out, int out_size, void* d_ws, size_t ws_size,
                              hipStream_t stream)
{
  const float* z = (const float*)d_in[0];
  const float* cb = (const float*)d_in[1];
  float* out = (float*)d_out;
  char* ws = (char*)d_ws;

  // ws layout (bytes)
  __hip_bfloat16* zh = (__hip_bfloat16*)(ws + 0);          // 16,777,216
  __hip_bfloat16* chv = (__hip_bfloat16*)(ws + 16777216);  //  4,194,304
  float* norms = (float*)(ws + 20971520);                  //    131,072 (padded)
  u64* pamin = (u64*)(ws + 21102592);                      // 16,777,216 (64 x 32768)
  uint32_t* codei = (uint32_t*)(ws + 37879808);            //    131,072
  float* lpart = (float*)(ws + 38010880);                  //     16,384
  // total: 38,027,264 bytes

  prep_all<<<3072, 256, 0, stream>>>(z, cb, zh, chv, norms);
  gemm_argmin<<<256, 512, 0, stream>>>(zh, chv, norms, pamin);
  reduce_amin<<<NROWS / 256, 256, 0, stream>>>(pamin, codei);
  gather_out<<<QELEMS / 2048, 256, 0, stream>>>(z, cb, codei, out, lpart);
  finalize<<<1, 256, 0, stream>>>(lpart, out);
}

// Round 12
// 197.623 us; speedup vs baseline: 3.1979x; 3.1979x over previous
//
#include <hip/hip_runtime.h>
#include <hip/hip_bf16.h>
#include <stdint.h>

typedef __attribute__((ext_vector_type(4))) float floatx4;
typedef __attribute__((ext_vector_type(2))) unsigned int uint2v;
typedef unsigned long long u64;

typedef __attribute__((address_space(1))) const uint32_t ga_u32;
typedef __attribute__((address_space(3))) uint32_t ls_u32;

static constexpr int NROWS = 32768;
static constexpr int NCODE = 8192;
static constexpr int QELEMS = 8388608;
static constexpr float CSCALE = 8192.0f;

// ---- fused prep: [0,1024) z->fp8 transpose, [1024,3072) codebook, [3072,3088) amin ----
__global__ __launch_bounds__(256) void prep_all(
    const float* __restrict__ z, const float* __restrict__ cb,
    unsigned char* __restrict__ z8, unsigned char* __restrict__ c8,
    float* __restrict__ norms, u64* __restrict__ amin)
{
  const int bid = blockIdx.x;
  const int t = threadIdx.x;
  if (bid < 1024) {
    __shared__ float tile[32][260];
    const int b = bid & 31, db = (bid >> 5) & 7, hwb = bid >> 8;
    const int d0 = db * 32, hw0 = hwb * 256;
    const float* src = z + (((size_t)b * 256 + d0) << 10) + hw0;
#pragma unroll
    for (int i = 0; i < 8; ++i) {
      int idx = i * 256 + t;
      int r = idx >> 6, c4 = (idx & 63) * 4;
      *(floatx4*)&tile[r][c4] = *(const floatx4*)&src[((size_t)r << 10) + c4];
    }
    __syncthreads();
    const int dq = t & 3;
    const int hb = t >> 2;
#pragma unroll
    for (int it = 0; it < 4; ++it) {
      int h = hb + it * 64;
      float f[8];
#pragma unroll
      for (int i = 0; i < 8; ++i) f[i] = tile[dq * 8 + i][h];
      int lo = __builtin_amdgcn_cvt_pk_fp8_f32(f[0], f[1], 0, false);
      lo = __builtin_amdgcn_cvt_pk_fp8_f32(f[2], f[3], lo, true);
      int hi = __builtin_amdgcn_cvt_pk_fp8_f32(f[4], f[5], 0, false);
      hi = __builtin_amdgcn_cvt_pk_fp8_f32(f[6], f[7], hi, true);
      uint2v o; o[0] = (unsigned)lo; o[1] = (unsigned)hi;
      *(uint2v*)&z8[((size_t)(b * 1024 + hw0 + h)) * 256 + d0 + dq * 8] = o;
    }
  } else if (bid < 3072) {
    const int k = (bid - 1024) * 4 + (t >> 6);
    const int lane = t & 63;
    floatx4 v = *(const floatx4*)&cb[((size_t)k << 8) + lane * 4];
    float a = v[0] * CSCALE, b2 = v[1] * CSCALE, c = v[2] * CSCALE, d2 = v[3] * CSCALE;
    int r = __builtin_amdgcn_cvt_pk_fp8_f32(a, b2, 0, false);
    r = __builtin_amdgcn_cvt_pk_fp8_f32(c, d2, r, true);
    *(unsigned int*)&c8[((size_t)k << 8) + lane * 4] = (unsigned)r;
    float s = a * a + b2 * b2 + c * c + d2 * d2;  // ||8192 c||^2
#pragma unroll
    for (int off = 32; off; off >>= 1) s += __shfl_down(s, off);
    if (lane == 0) norms[k] = s;
  } else {
    const int base = (bid - 3072) * 2048;
#pragma unroll
    for (int i = 0; i < 8; ++i) amin[base + i * 256 + t] = ~0ull;
  }
}

// ---- main: fp8 GEMM, 128x256 tile, 4 waves, BK=64, 3-slot ring, 2 blocks/CU ----
// Wave tile 64 codes x 128 zrows, acc[4][8]. Per kt: 24 ds_read_b64 + 64 MFMA
// per wave; 6 global_load_lds/thread; counted vmcnt(6); 1 barrier/kt (4 total).
__global__ __launch_bounds__(256, 2) void gemm_argmin(
    const unsigned char* __restrict__ z8, const unsigned char* __restrict__ c8,
    const float* __restrict__ norms, u64* __restrict__ amin)
{
  // slot = 24576 B: A[128][64] fp8 at +0, B[256][64] at +8192; best2 at +73728
  __shared__ alignas(16) unsigned char lds8[3 * 24576 + 4096];

  const int tid = threadIdx.x;
  const int lane = tid & 63;
  const int wid = tid >> 6;
  const int wm = wid >> 1;  // code half (64 codes)
  const int wn = wid & 1;   // zrow half (128 zrows)

  // XCD chunked swizzle: nwg = 8192 (%8 == 0)
  const int bid = blockIdx.x;
  const int swz = (bid & 7) * 1024 + (bid >> 3);
  const int cx = swz & 63;   // 64 code panels
  const int cy = swz >> 6;   // 128 zrow panels
  const int m0 = cx * 128;
  const int n0 = cy * 256;

  const int q = lane & 15;
  const int g = lane >> 4;
  const int pcx = ((q >> 1) & 3) << 1;  // read-side 8B-chunk XOR (involution)

  floatx4 acc[4][8];
#pragma unroll
  for (int i = 0; i < 4; ++i)
#pragma unroll
    for (int j = 0; j < 8; ++j)
      acc[i][j] = (floatx4){0.f, 0.f, 0.f, 0.f};

  auto STAGE = [&](int kt) {  // 6 x global_load_lds(16B): A 8KB + B 16KB
    unsigned char* sbase = lds8 + (kt % 3) * 24576;
#pragma unroll
    for (int p = 0; p < 2; ++p) {  // A
      int flat = p * 256 + tid;
      int row = flat >> 2, s = flat & 3;
      int ps = s ^ ((row >> 1) & 3);  // source-side 16B-slot XOR (involution)
      const unsigned char* gp = c8 + ((size_t)(m0 + row) << 8) + kt * 64 + ps * 16;
      __builtin_amdgcn_global_load_lds((ga_u32*)gp, (ls_u32*)(sbase + flat * 16), 16, 0, 0);
    }
#pragma unroll
    for (int p = 0; p < 4; ++p) {  // B
      int flat = p * 256 + tid;
      int row = flat >> 2, s = flat & 3;
      int ps = s ^ ((row >> 1) & 3);
      const unsigned char* gp = z8 + ((size_t)(n0 + row) << 8) + kt * 64 + ps * 16;
      __builtin_amdgcn_global_load_lds((ga_u32*)gp, (ls_u32*)(sbase + 8192 + flat * 16), 16, 0, 0);
    }
  };

  // prologue: stage kt0, kt1; drain kt0 (kt1's 6 stay in flight)
  STAGE(0); STAGE(1);
  asm volatile("s_waitcnt vmcnt(6)" ::: "memory");
  __builtin_amdgcn_s_barrier();
  asm volatile("" ::: "memory");

#pragma unroll
  for (int kt = 0; kt < 4; ++kt) {
    const unsigned char* sbase = lds8 + (kt % 3) * 24576;
    long af[4][2], bf[8][2];
#pragma unroll
    for (int i = 0; i < 4; ++i)
#pragma unroll
      for (int ks = 0; ks < 2; ++ks) {
        int row = wm * 64 + i * 16 + q;
        int pc = (ks * 4 + g) ^ pcx;
        af[i][ks] = *(const long*)(sbase + row * 64 + pc * 8);
      }
#pragma unroll
    for (int j = 0; j < 8; ++j)
#pragma unroll
      for (int ks = 0; ks < 2; ++ks) {
        int row = wn * 128 + j * 16 + q;
        int pc = (ks * 4 + g) ^ pcx;
        bf[j][ks] = *(const long*)(sbase + 8192 + row * 64 + pc * 8);
      }
    if (kt < 2) STAGE(kt + 2);
    __builtin_amdgcn_s_setprio(1);
#pragma unroll
    for (int ks = 0; ks < 2; ++ks)
#pragma unroll
      for (int i = 0; i < 4; ++i)
#pragma unroll
        for (int j = 0; j < 8; ++j)
          acc[i][j] = __builtin_amdgcn_mfma_f32_16x16x32_fp8_fp8(af[i][ks], bf[j][ks], acc[i][j], 0, 0, 0);
    __builtin_amdgcn_s_setprio(0);
    // boundary: drain stage(kt+1), keep stage(kt+2)'s 6 in flight
    if (kt < 2)       asm volatile("s_waitcnt vmcnt(6)" ::: "memory");
    else if (kt == 2) asm volatile("s_waitcnt vmcnt(0)" ::: "memory");
    if (kt < 3) {
      asm volatile("" ::: "memory");
      __builtin_amdgcn_s_barrier();
      asm volatile("" ::: "memory");
    }
  }

  // ---- epilogue: fused argmin in scaled space; ties -> smallest code ----
  float nrm[4][4];
#pragma unroll
  for (int i = 0; i < 4; ++i)
#pragma unroll
    for (int r = 0; r < 4; ++r)
      nrm[i][r] = norms[m0 + wm * 64 + i * 16 + g * 4 + r];

  u64* best2 = (u64*)(lds8 + 3 * 24576);  // [256 zrows][2 wm]
#pragma unroll
  for (int j = 0; j < 8; ++j) {
    float best = __builtin_inff();
    int bc = 0;
    // scaled score = ||c'||^2 - 16384*(z . c'); ascending code order
#pragma unroll
    for (int i = 0; i < 4; ++i)
#pragma unroll
      for (int r = 0; r < 4; ++r) {
        float sc = fmaf(acc[i][j][r], -16384.f, nrm[i][r]);
        int cd = m0 + wm * 64 + i * 16 + g * 4 + r;
        if (sc < best) { best = sc; bc = cd; }
      }
    uint32_t u = __float_as_uint(best);
    u ^= ((uint32_t)((int32_t)u >> 31) | 0x80000000u);  // monotone-sortable
    u64 p = ((u64)u << 32) | (uint32_t)bc;
#pragma unroll
    for (int off = 16; off < 64; off <<= 1) {
      u64 o = (u64)__shfl_xor((long long)p, off);
      p = o < p ? o : p;
    }
    if (lane < 16) best2[(size_t)(wn * 128 + j * 16 + lane) * 2 + wm] = p;
  }
  __syncthreads();
  {
    u64 a = best2[tid * 2], b = best2[tid * 2 + 1];
    u64 p = a < b ? a : b;
    atomicMin(&amin[n0 + tid], p);
  }
}

// ---- gather + output + per-block loss partials (8 elems/thread, amin direct) ----
__global__ __launch_bounds__(256) void gather_out(
    const float* __restrict__ z, const float* __restrict__ cb,
    const u64* __restrict__ amin,
    float* __restrict__ out, float* __restrict__ partial)
{
  const int t = threadIdx.x;
  const size_t e0 = ((size_t)blockIdx.x * 256 + t) * 8;
  const int d = (int)((e0 >> 10) & 255);
  const int b = (int)(e0 >> 18);
  const int n0 = b * 1024 + (int)(e0 & 1023);
  uint32_t kv[8];
#pragma unroll
  for (int m = 0; m < 8; ++m) kv[m] = (uint32_t)amin[n0 + m];
  floatx4 z0 = *(const floatx4*)&z[e0];
  floatx4 z1 = *(const floatx4*)&z[e0 + 4];
  floatx4 q0, q1;
#pragma unroll
  for (int m = 0; m < 4; ++m) {
    q0[m] = cb[((size_t)kv[m] << 8) + d];
    q1[m] = cb[((size_t)kv[4 + m] << 8) + d];
  }
  *(floatx4*)&out[e0] = q0;
  *(floatx4*)&out[e0 + 4] = q1;
  float s = 0.f;
#pragma unroll
  for (int m = 0; m < 4; ++m) {
    float d0 = z0[m] - q0[m], d1 = z1[m] - q1[m];
    s += d0 * d0 + d1 * d1;
  }
#pragma unroll
  for (int off = 32; off; off >>= 1) s += __shfl_down(s, off);
  __shared__ float ps[4];
  if ((t & 63) == 0) ps[t >> 6] = s;
  __syncthreads();
  if (t == 0) partial[blockIdx.x] = ps[0] + ps[1] + ps[2] + ps[3];
}

// ---- deterministic final reduction + scalar outputs ----
__global__ __launch_bounds__(256) void finalize(const float* __restrict__ partial,
                                                float* __restrict__ out)
{
  const int t = threadIdx.x;
  float s = 0.f;
#pragma unroll
  for (int i = 0; i < 16; ++i) s += partial[i * 256 + t];
#pragma unroll
  for (int off = 32; off; off >>= 1) s += __shfl_down(s, off);
  __shared__ float ps[4];
  if ((t & 63) == 0) ps[t >> 6] = s;
  __syncthreads();
  if (t == 0) {
    float m = (ps[0] + ps[1] + ps[2] + ps[3]) / (float)QELEMS;
    out[QELEMS] = m;             // codebook_loss
    out[QELEMS + 1] = 0.2f * m;  // commitment_loss
  }
}

extern "C" void kernel_launch(void* const* d_in, const int* in_sizes, int n_in,
                              void* d_out, int out_size, void* d_ws, size_t ws_size,
                              hipStream_t stream)
{
  const float* z = (const float*)d_in[0];
  const float* cb = (const float*)d_in[1];
  float* out = (float*)d_out;
  char* ws = (char*)d_ws;

  // ws layout (bytes)
  unsigned char* z8 = (unsigned char*)(ws + 0);       //  8,388,608
  unsigned char* c8 = (unsigned char*)(ws + 8388608); //  2,097,152
  float* norms = (float*)(ws + 10485760);             //    131,072 (padded)
  u64* amin = (u64*)(ws + 10616832);                  //    262,144
  float* lpart = (float*)(ws + 10878976);             //     16,384
  // total: 10,895,360 bytes

  prep_all<<<3088, 256, 0, stream>>>(z, cb, z8, c8, norms, amin);
  gemm_argmin<<<8192, 256, 0, stream>>>(z8, c8, norms, amin);
  gather_out<<<QELEMS / 2048, 256, 0, stream>>>(z, cb, amin, out, lpart);
  finalize<<<1, 256, 0, stream>>>(lpart, out);
}

// Round 13
// 160.969 us; speedup vs baseline: 3.9261x; 1.2277x over previous
//
#include <hip/hip_runtime.h>
#include <hip/hip_bf16.h>
#include <stdint.h>

typedef __attribute__((ext_vector_type(4))) float floatx4;
typedef __attribute__((ext_vector_type(16))) float floatx16;
typedef __attribute__((ext_vector_type(4))) int intx4;
typedef __attribute__((ext_vector_type(8))) int intx8;
typedef __attribute__((ext_vector_type(2))) unsigned int uint2v;
typedef unsigned long long u64;

typedef __attribute__((address_space(1))) const uint32_t ga_u32;
typedef __attribute__((address_space(3))) uint32_t ls_u32;

static constexpr int NROWS = 32768;
static constexpr int NCODE = 8192;
static constexpr int QELEMS = 8388608;
static constexpr float CSCALE = 8192.0f;

// ---- fused prep: [0,1024) z->fp8 transpose, [1024,3072) codebook, [3072,3088) amin ----
__global__ __launch_bounds__(256) void prep_all(
    const float* __restrict__ z, const float* __restrict__ cb,
    unsigned char* __restrict__ z8, unsigned char* __restrict__ c8,
    float* __restrict__ norms, u64* __restrict__ amin)
{
  const int bid = blockIdx.x;
  const int t = threadIdx.x;
  if (bid < 1024) {
    __shared__ float tile[32][260];
    const int b = bid & 31, db = (bid >> 5) & 7, hwb = bid >> 8;
    const int d0 = db * 32, hw0 = hwb * 256;
    const float* src = z + (((size_t)b * 256 + d0) << 10) + hw0;
#pragma unroll
    for (int i = 0; i < 8; ++i) {
      int idx = i * 256 + t;
      int r = idx >> 6, c4 = (idx & 63) * 4;
      *(floatx4*)&tile[r][c4] = *(const floatx4*)&src[((size_t)r << 10) + c4];
    }
    __syncthreads();
    const int dq = t & 3;
    const int hb = t >> 2;
#pragma unroll
    for (int it = 0; it < 4; ++it) {
      int h = hb + it * 64;
      float f[8];
#pragma unroll
      for (int i = 0; i < 8; ++i) f[i] = tile[dq * 8 + i][h];
      int lo = __builtin_amdgcn_cvt_pk_fp8_f32(f[0], f[1], 0, false);
      lo = __builtin_amdgcn_cvt_pk_fp8_f32(f[2], f[3], lo, true);
      int hi = __builtin_amdgcn_cvt_pk_fp8_f32(f[4], f[5], 0, false);
      hi = __builtin_amdgcn_cvt_pk_fp8_f32(f[6], f[7], hi, true);
      uint2v o; o[0] = (unsigned)lo; o[1] = (unsigned)hi;
      *(uint2v*)&z8[((size_t)(b * 1024 + hw0 + h)) * 256 + d0 + dq * 8] = o;
    }
  } else if (bid < 3072) {
    const int k = (bid - 1024) * 4 + (t >> 6);
    const int lane = t & 63;
    floatx4 v = *(const floatx4*)&cb[((size_t)k << 8) + lane * 4];
    float a = v[0] * CSCALE, b2 = v[1] * CSCALE, c = v[2] * CSCALE, d2 = v[3] * CSCALE;
    int r = __builtin_amdgcn_cvt_pk_fp8_f32(a, b2, 0, false);
    r = __builtin_amdgcn_cvt_pk_fp8_f32(c, d2, r, true);
    *(unsigned int*)&c8[((size_t)k << 8) + lane * 4] = (unsigned)r;
    float s = a * a + b2 * b2 + c * c + d2 * d2;  // ||8192 c||^2
#pragma unroll
    for (int off = 32; off; off >>= 1) s += __shfl_down(s, off);
    if (lane == 0) norms[k] = s;
  } else {
    const int base = (bid - 3072) * 2048;
#pragma unroll
    for (int i = 0; i < 8; ++i) amin[base + i * 256 + t] = ~0ull;
  }
}

// ---- main: MX-fp8 32x32x64 GEMM (scale=1), 128x256 tile, 4 waves, BK=64 ----
// 3-slot ring, 2 blocks/CU, counted vmcnt(6), 1 barrier/kt. Wave 64x128:
// acc[2][4] floatx16 (128 AGPR). 12 conflict-free ds_read_b128 + 8 MFMA /wave/kt.
__global__ __launch_bounds__(256, 2) void gemm_argmin(
    const unsigned char* __restrict__ z8, const unsigned char* __restrict__ c8,
    const float* __restrict__ norms, u64* __restrict__ amin)
{
  // slot = 24576 B: A[128][64] fp8 at +0, B[256][64] at +8192; best2 at +73728
  __shared__ alignas(16) unsigned char lds8[3 * 24576 + 4096];

  const int tid = threadIdx.x;
  const int lane = tid & 63;
  const int wid = tid >> 6;
  const int wm = wid >> 1;  // code half (64 codes)
  const int wn = wid & 1;   // zrow half (128 zrows)

  // XCD chunked swizzle: nwg = 8192 (%8 == 0)
  const int bid = blockIdx.x;
  const int swz = (bid & 7) * 1024 + (bid >> 3);
  const int cx = swz & 63;   // 64 code panels
  const int cy = swz >> 6;   // 128 zrow panels
  const int m0 = cx * 128;
  const int n0 = cy * 256;

  const int l31 = lane & 31;
  const int hi = lane >> 5;
  const int k2 = hi << 1;    // logical 16B-slot base (2k)

  floatx16 acc[2][4];
#pragma unroll
  for (int i = 0; i < 2; ++i)
#pragma unroll
    for (int j = 0; j < 4; ++j)
#pragma unroll
      for (int e = 0; e < 16; ++e) acc[i][j][e] = 0.f;

  auto STAGE = [&](int kt) {  // 6 x global_load_lds(16B): A 8KB + B 16KB
    unsigned char* sbase = lds8 + (kt % 3) * 24576;
#pragma unroll
    for (int p = 0; p < 2; ++p) {  // A
      int flat = p * 256 + tid;
      int row = flat >> 2, s = flat & 3;
      int ps = s ^ ((row >> 1) & 3);  // source slot (involution)
      const unsigned char* gp = c8 + ((size_t)(m0 + row) << 8) + kt * 64 + ps * 16;
      __builtin_amdgcn_global_load_lds((ga_u32*)gp, (ls_u32*)(sbase + flat * 16), 16, 0, 0);
    }
#pragma unroll
    for (int p = 0; p < 4; ++p) {  // B
      int flat = p * 256 + tid;
      int row = flat >> 2, s = flat & 3;
      int ps = s ^ ((row >> 1) & 3);
      const unsigned char* gp = z8 + ((size_t)(n0 + row) << 8) + kt * 64 + ps * 16;
      __builtin_amdgcn_global_load_lds((ga_u32*)gp, (ls_u32*)(sbase + 8192 + flat * 16), 16, 0, 0);
    }
  };

  // read one 32B operand fragment (row-major, swizzled slots) as v8i32
  auto RDOP = [&](const unsigned char* rbase, int row) -> intx8 {
    const int v = (row >> 1) & 3;
    intx4 lo = *(const intx4*)(rbase + row * 64 + ((k2 ^ v) << 4));
    intx4 hv = *(const intx4*)(rbase + row * 64 + (((k2 + 1) ^ v) << 4));
    intx8 o;
#pragma unroll
    for (int w = 0; w < 4; ++w) { o[w] = lo[w]; o[4 + w] = hv[w]; }
    return o;
  };

  // prologue: stage kt0, kt1; drain kt0 (kt1's 6 stay in flight)
  STAGE(0); STAGE(1);
  asm volatile("s_waitcnt vmcnt(6)" ::: "memory");
  __builtin_amdgcn_s_barrier();
  asm volatile("" ::: "memory");

#pragma unroll
  for (int kt = 0; kt < 4; ++kt) {
    unsigned char* sbase = lds8 + (kt % 3) * 24576;
    intx8 af[2], bf[4];
#pragma unroll
    for (int ti = 0; ti < 2; ++ti)
      af[ti] = RDOP(sbase, wm * 64 + ti * 32 + l31);
#pragma unroll
    for (int tj = 0; tj < 4; ++tj)
      bf[tj] = RDOP(sbase + 8192, wn * 128 + tj * 32 + l31);
    if (kt < 2) STAGE(kt + 2);
    __builtin_amdgcn_s_setprio(1);
#pragma unroll
    for (int ti = 0; ti < 2; ++ti)
#pragma unroll
      for (int tj = 0; tj < 4; ++tj)
        acc[ti][tj] = __builtin_amdgcn_mfma_scale_f32_32x32x64_f8f6f4(
            af[ti], bf[tj], acc[ti][tj], 0, 0, 0, 127, 0, 127);
    __builtin_amdgcn_s_setprio(0);
    // boundary: drain stage(kt+1), keep stage(kt+2)'s 6 in flight
    if (kt < 2)       asm volatile("s_waitcnt vmcnt(6)" ::: "memory");
    else if (kt == 2) asm volatile("s_waitcnt vmcnt(0)" ::: "memory");
    if (kt < 3) {
      asm volatile("" ::: "memory");
      __builtin_amdgcn_s_barrier();
      asm volatile("" ::: "memory");
    }
  }

  // ---- epilogue: fused argmin in scaled space; ties -> smallest code ----
  // D layout: zrow = lane&31; code-in-tile = (reg&3) + 8*(reg>>2) + 4*hi
  floatx4 nv[2][4];
#pragma unroll
  for (int ti = 0; ti < 2; ++ti)
#pragma unroll
    for (int rq = 0; rq < 4; ++rq)
      nv[ti][rq] = *(const floatx4*)&norms[m0 + wm * 64 + ti * 32 + rq * 8 + 4 * hi];

  u64* best2 = (u64*)(lds8 + 3 * 24576);  // [256 zrows][2 wm]
#pragma unroll
  for (int tj = 0; tj < 4; ++tj) {
    float best = __builtin_inff();
    int bc = 0;
    // ascending code order within lane: ti, rq, rl
#pragma unroll
    for (int ti = 0; ti < 2; ++ti)
#pragma unroll
      for (int rq = 0; rq < 4; ++rq)
#pragma unroll
        for (int rl = 0; rl < 4; ++rl) {
          float sc = fmaf(acc[ti][tj][rq * 4 + rl], -16384.f, nv[ti][rq][rl]);
          int cd = m0 + wm * 64 + ti * 32 + rq * 8 + 4 * hi + rl;
          if (sc < best) { best = sc; bc = cd; }
        }
    uint32_t u = __float_as_uint(best);
    u ^= ((uint32_t)((int32_t)u >> 31) | 0x80000000u);  // monotone-sortable
    u64 p = ((u64)u << 32) | (uint32_t)bc;
    {
      u64 o = (u64)__shfl_xor((long long)p, 32);
      p = o < p ? o : p;
    }
    if (lane < 32) best2[(size_t)(wn * 128 + tj * 32 + l31) * 2 + wm] = p;
  }
  __syncthreads();
  {
    u64 a = best2[tid * 2], b = best2[tid * 2 + 1];
    u64 p = a < b ? a : b;
    atomicMin(&amin[n0 + tid], p);
  }
}

// ---- gather + output + per-block loss partials (8 elems/thread, amin direct) ----
__global__ __launch_bounds__(256) void gather_out(
    const float* __restrict__ z, const float* __restrict__ cb,
    const u64* __restrict__ amin,
    float* __restrict__ out, float* __restrict__ partial)
{
  const int t = threadIdx.x;
  const size_t e0 = ((size_t)blockIdx.x * 256 + t) * 8;
  const int d = (int)((e0 >> 10) & 255);
  const int b = (int)(e0 >> 18);
  const int n0 = b * 1024 + (int)(e0 & 1023);
  uint32_t kv[8];
#pragma unroll
  for (int m = 0; m < 8; ++m) kv[m] = (uint32_t)amin[n0 + m];
  floatx4 z0 = *(const floatx4*)&z[e0];
  floatx4 z1 = *(const floatx4*)&z[e0 + 4];
  floatx4 q0, q1;
#pragma unroll
  for (int m = 0; m < 4; ++m) {
    q0[m] = cb[((size_t)kv[m] << 8) + d];
    q1[m] = cb[((size_t)kv[4 + m] << 8) + d];
  }
  *(floatx4*)&out[e0] = q0;
  *(floatx4*)&out[e0 + 4] = q1;
  float s = 0.f;
#pragma unroll
  for (int m = 0; m < 4; ++m) {
    float d0 = z0[m] - q0[m], d1 = z1[m] - q1[m];
    s += d0 * d0 + d1 * d1;
  }
#pragma unroll
  for (int off = 32; off; off >>= 1) s += __shfl_down(s, off);
  __shared__ float ps[4];
  if ((t & 63) == 0) ps[t >> 6] = s;
  __syncthreads();
  if (t == 0) partial[blockIdx.x] = ps[0] + ps[1] + ps[2] + ps[3];
}

// ---- deterministic final reduction + scalar outputs ----
__global__ __launch_bounds__(256) void finalize(const float* __restrict__ partial,
                                                float* __restrict__ out)
{
  const int t = threadIdx.x;
  float s = 0.f;
#pragma unroll
  for (int i = 0; i < 16; ++i) s += partial[i * 256 + t];
#pragma unroll
  for (int off = 32; off; off >>= 1) s += __shfl_down(s, off);
  __shared__ float ps[4];
  if ((t & 63) == 0) ps[t >> 6] = s;
  __syncthreads();
  if (t == 0) {
    float m = (ps[0] + ps[1] + ps[2] + ps[3]) / (float)QELEMS;
    out[QELEMS] = m;             // codebook_loss
    out[QELEMS + 1] = 0.2f * m;  // commitment_loss
  }
}

extern "C" void kernel_launch(void* const* d_in, const int* in_sizes, int n_in,
                              void* d_out, int out_size, void* d_ws, size_t ws_size,
                              hipStream_t stream)
{
  const float* z = (const float*)d_in[0];
  const float* cb = (const float*)d_in[1];
  float* out = (float*)d_out;
  char* ws = (char*)d_ws;

  // ws layout (bytes)
  unsigned char* z8 = (unsigned char*)(ws + 0);       //  8,388,608
  unsigned char* c8 = (unsigned char*)(ws + 8388608); //  2,097,152
  float* norms = (float*)(ws + 10485760);             //    131,072 (padded)
  u64* amin = (u64*)(ws + 10616832);                  //    262,144
  float* lpart = (float*)(ws + 10878976);             //     16,384
  // total: 10,895,360 bytes

  prep_all<<<3088, 256, 0, stream>>>(z, cb, z8, c8, norms, amin);
  gemm_argmin<<<8192, 256, 0, stream>>>(z8, c8, norms, amin);
  gather_out<<<QELEMS / 2048, 256, 0, stream>>>(z, cb, amin, out, lpart);
  finalize<<<1, 256, 0, stream>>>(lpart, out);
}